// Round 1
// baseline (1778.377 us; speedup 1.0000x reference)
//
#include <hip/hip_runtime.h>
#include <stdint.h>

// Workspace requirement: ~302 MB (adj_bf16 207MB + split-K partials 41MB + misc).
//
// Pipeline:
//  k_rowops    : x -> x_hi/x_lo bf16 (split precision), sq norms, h2_0 = x
//  k_transpose : x -> x^T fp32 + h^T fp32/bf16 init (propagation kept in [feat][node])
//  k_adjcvt    : adj fp32 -> bf16, padded [10112][10240], zeroed pads
//  k_gram      : fused hi/lo-MFMA Gram + per-lane running top-16 (4 j-splits)
//  k_merge     : wave-per-query exact merge of 256 candidates -> knn idx
//  5x k_knnprop: sparse propagation (16 nbrs)
//  5x (k_gemm split-K=8 MFMA + k_reduce): dense propagation h = 0.5*adj@h + 0.5*x
//  k_enc x2, k_zres: encoders + decoder (fp32 VALU, tiny)
//  k_out2      : res @ res^T via bf16 MFMA, write-bound

typedef unsigned short u16;
typedef unsigned int u32;

#define N_NODES 10000
#define NPAD    10112   // 79*128  (M/row padding)
#define KPAD    10240   // 8*1280  (K padding for split-K)
#define JPAD    10240   // 4*2560  (kNN candidate padding)
#define NF      128
#define NH      64

using short8 = __attribute__((ext_vector_type(8))) short;
using f32x4  = __attribute__((ext_vector_type(4))) float;

__device__ __forceinline__ u16 f2bf(float f) {
  u32 u = __float_as_uint(f);
  u += 0x7FFFu + ((u >> 16) & 1u);
  return (u16)(u >> 16);
}
__device__ __forceinline__ float bf2f(u16 h) { return __uint_as_float(((u32)h) << 16); }

__device__ __forceinline__ void g2lds16(const void* g, void* l) {
  __builtin_amdgcn_global_load_lds((const __attribute__((address_space(1))) void*)g,
                                   (__attribute__((address_space(3))) void*)l, 16, 0, 0);
}

// ---------------- setup kernels ----------------

__global__ __launch_bounds__(256) void k_rowops(const float* __restrict__ x,
    u16* __restrict__ xhi, u16* __restrict__ xlo, float* __restrict__ sq,
    float* __restrict__ h2a) {
  int w = threadIdx.x >> 6, lane = threadIdx.x & 63;
  int row = blockIdx.x * 4 + w;
  if (row >= JPAD) return;
  int f = lane * 2;
  if (row < N_NODES) {
    float2 v = *(const float2*)(x + (size_t)row * NF + f);
    u16 h0 = f2bf(v.x), h1 = f2bf(v.y);
    float l0 = v.x - bf2f(h0), l1 = v.y - bf2f(h1);
    u16 e0 = f2bf(l0), e1 = f2bf(l1);
    *(u32*)(xhi + (size_t)row * NF + f) = (u32)h0 | ((u32)h1 << 16);
    *(u32*)(xlo + (size_t)row * NF + f) = (u32)e0 | ((u32)e1 << 16);
    *(float2*)(h2a + (size_t)row * NF + f) = v;
    float s = v.x * v.x + v.y * v.y;
#pragma unroll
    for (int o = 32; o > 0; o >>= 1) s += __shfl_xor(s, o);
    if (lane == 0) sq[row] = s;
  } else {
    *(u32*)(xhi + (size_t)row * NF + f) = 0u;
    *(u32*)(xlo + (size_t)row * NF + f) = 0u;
    if (lane == 0) sq[row] = 0.f;
  }
}

__global__ __launch_bounds__(256) void k_transpose(const float* __restrict__ x,
    float* __restrict__ xTf, float* __restrict__ hTf, u16* __restrict__ hTb) {
  __shared__ float tile[32][33];
  int k0 = blockIdx.x * 32, f0 = blockIdx.y * 32;
  int c = threadIdx.x & 31, r4 = threadIdx.x >> 5;
#pragma unroll
  for (int i = 0; i < 4; i++) {
    int r = r4 + i * 8;
    int k = k0 + r;
    float v = 0.f;
    if (k < N_NODES) v = x[(size_t)k * NF + f0 + c];
    tile[r][c] = v;
  }
  __syncthreads();
#pragma unroll
  for (int i = 0; i < 4; i++) {
    int r = r4 + i * 8;
    int f = f0 + r;
    int k = k0 + c;
    float v = tile[c][r];
    size_t idx = (size_t)f * KPAD + k;
    xTf[idx] = v; hTf[idx] = v; hTb[idx] = f2bf(v);
  }
}

__global__ __launch_bounds__(256) void k_adjcvt(const float* __restrict__ adj,
                                                u16* __restrict__ out) {
  const int UNITS = NPAD * (KPAD / 8);
  for (int u = blockIdx.x * 256 + threadIdx.x; u < UNITS; u += gridDim.x * 256) {
    int r = u / (KPAD / 8);
    int c = (u - r * (KPAD / 8)) * 8;
    u16 o[8];
    if (r < N_NODES && c + 7 < N_NODES) {
      const float* p = adj + (size_t)r * N_NODES + c;
      float4 a = *(const float4*)p;
      float4 b = *(const float4*)(p + 4);
      o[0]=f2bf(a.x); o[1]=f2bf(a.y); o[2]=f2bf(a.z); o[3]=f2bf(a.w);
      o[4]=f2bf(b.x); o[5]=f2bf(b.y); o[6]=f2bf(b.z); o[7]=f2bf(b.w);
    } else {
#pragma unroll
      for (int t = 0; t < 8; t++) {
        int cc = c + t;
        o[t] = (r < N_NODES && cc < N_NODES) ? f2bf(adj[(size_t)r * N_NODES + cc]) : (u16)0;
      }
    }
    uint4 pk;
    pk.x = (u32)o[0] | ((u32)o[1] << 16);
    pk.y = (u32)o[2] | ((u32)o[3] << 16);
    pk.z = (u32)o[4] | ((u32)o[5] << 16);
    pk.w = (u32)o[6] | ((u32)o[7] << 16);
    *(uint4*)(out + (size_t)r * KPAD + c) = pk;
  }
}

// ---------------- kNN: fused gram + top-16 ----------------
// grid (158, 4): 64 queries/block (wave w owns q = bx*64 + w*16 + (lane&15)),
// split covers j in [split*2560, split*2560+2560). Ranking key d' = sq_j - 2*dot.

__global__ __launch_bounds__(256) void k_gram(const u16* __restrict__ xhi,
    const u16* __restrict__ xlo, const float* __restrict__ sqg,
    float2* __restrict__ cand) {
  __shared__ __align__(16) u16 shi[64 * 128];
  __shared__ __align__(16) u16 slo[64 * 128];
  __shared__ __align__(16) float ssq[64];
  const int tid = threadIdx.x, w = tid >> 6, lane = tid & 63;
  const int l15 = lane & 15, g = lane >> 4;
  const int q = blockIdx.x * 64 + w * 16 + l15;
  const int split = blockIdx.y;

  short8 bh[4], bl[4];
#pragma unroll
  for (int ks = 0; ks < 4; ks++) {
    size_t off = (size_t)q * NF + ks * 32 + g * 8;
    bh[ks] = *(const short8*)(xhi + off);
    bl[ks] = *(const short8*)(xlo + off);
  }
  float t[16]; int ti[16];
#pragma unroll
  for (int i = 0; i < 16; i++) { t[i] = 3.0e38f; ti[i] = -1; }
  float thr = 3.0e38f;

  for (int ch = 0; ch < 40; ch++) {
    int jbase = split * 2560 + ch * 64;
    __syncthreads();
    // stage 64 j-rows (hi+lo) with 16B-unit XOR swizzle
#pragma unroll
    for (int r = 0; r < 4; r++) {
      int s = r * 256 + tid;
      int row = s >> 4, u = s & 15;
      int uu = u ^ (row & 7);
      size_t goff = (size_t)(jbase + row) * NF + uu * 8;
      g2lds16(xhi + goff, (void*)(shi + ((s & ~63) << 3)));
      g2lds16(xlo + goff, (void*)(slo + ((s & ~63) << 3)));
    }
    if (tid < 64) ssq[tid] = sqg[jbase + tid];
    __syncthreads();

#pragma unroll
    for (int sub = 0; sub < 4; sub++) {
      f32x4 acc = {0.f, 0.f, 0.f, 0.f};
#pragma unroll
      for (int ks = 0; ks < 4; ks++) {
        int row = sub * 16 + l15;
        int uu = ((ks * 4 + g) ^ (row & 7));
        int idx = row * 128 + uu * 8;
        short8 ah = *(const short8*)(shi + idx);
        short8 al = *(const short8*)(slo + idx);
        acc = __builtin_amdgcn_mfma_f32_16x16x32_bf16(ah, bh[ks], acc, 0, 0, 0);
        acc = __builtin_amdgcn_mfma_f32_16x16x32_bf16(ah, bl[ks], acc, 0, 0, 0);
        acc = __builtin_amdgcn_mfma_f32_16x16x32_bf16(al, bh[ks], acc, 0, 0, 0);
      }
      f32x4 sv = *(const f32x4*)(ssq + sub * 16 + g * 4);
      int jb = jbase + sub * 16 + g * 4;
      float d[4];
#pragma unroll
      for (int reg = 0; reg < 4; reg++) {
        int j = jb + reg;
        float dd = sv[reg] - 2.0f * acc[reg];
        bool bad = (j >= N_NODES) || (j == q);
        d[reg] = bad ? 3.0e38f : dd;
      }
      float dmin = fminf(fminf(d[0], d[1]), fminf(d[2], d[3]));
      if (dmin < thr) {
#pragma unroll
        for (int reg = 0; reg < 4; reg++) {
          float dd = d[reg];
          if (dd < thr) {
            int j = jb + reg;
#pragma unroll
            for (int i = 15; i >= 1; --i) {
              bool ltp = dd < t[i - 1];
              bool ltc = dd < t[i];
              t[i]  = ltp ? t[i - 1] : (ltc ? dd : t[i]);
              ti[i] = ltp ? ti[i - 1] : (ltc ? j : ti[i]);
            }
            if (dd < t[0]) { t[0] = dd; ti[0] = j; }
          }
        }
      }
    }
    // shared (conservative) threshold across the 4 lanes of each query
    float th2 = t[15];
    th2 = fminf(th2, __shfl_xor(th2, 16));
    th2 = fminf(th2, __shfl_xor(th2, 32));
    thr = th2;
  }
  size_t base = (((size_t)q * 4 + split) * 4 + g) * 16;
#pragma unroll
  for (int i = 0; i < 16; i++)
    cand[base + i] = make_float2(t[i], __int_as_float(ti[i]));
}

__global__ __launch_bounds__(256) void k_merge(const float2* __restrict__ cand,
                                               int* __restrict__ knn) {
  int w = threadIdx.x >> 6, lane = threadIdx.x & 63;
  int q = blockIdx.x * 4 + w;
  if (q >= N_NODES) return;
  const float2* p = cand + (size_t)q * 256 + lane * 4;
  float hd[4]; int hj[4];
#pragma unroll
  for (int i = 0; i < 4; i++) { float2 v = p[i]; hd[i] = v.x; hj[i] = __float_as_int(v.y); }
  int myout = -1;
#pragma unroll
  for (int round = 0; round < 16; round++) {
    float d0 = hd[0]; int j0 = hj[0];
#pragma unroll
    for (int off = 32; off > 0; off >>= 1) {
      float dn = __shfl_xor(d0, off); int jn = __shfl_xor(j0, off);
      bool take = (dn < d0) || (dn == d0 && jn < j0);
      d0 = take ? dn : d0; j0 = take ? jn : j0;
    }
    if (hj[0] == j0) {  // j unique -> exactly one lane pops
      hd[0] = hd[1]; hj[0] = hj[1];
      hd[1] = hd[2]; hj[1] = hj[2];
      hd[2] = hd[3]; hj[2] = hj[3];
      hd[3] = 3.0e38f; hj[3] = -2;
    }
    if (lane == round) myout = j0;
  }
  if (lane < 16) knn[q * 16 + lane] = myout;
}

__global__ __launch_bounds__(256) void k_knnprop(const float* __restrict__ src,
    const float* __restrict__ x, const int* __restrict__ knn, float* __restrict__ dst) {
  int w = threadIdx.x >> 6, lane = threadIdx.x & 63;
  int row = blockIdx.x * 4 + w;
  if (row >= N_NODES) return;
  int f = lane * 2;
  float a0 = 0.f, a1 = 0.f;
#pragma unroll
  for (int nb = 0; nb < 16; nb++) {
    int j = knn[row * 16 + nb];
    float2 v = *(const float2*)(src + (size_t)j * NF + f);
    a0 += v.x; a1 += v.y;
  }
  float2 xv = *(const float2*)(x + (size_t)row * NF + f);
  float2 o;
  o.x = a0 * (0.5f / 16.f) + 0.5f * xv.x;
  o.y = a1 * (0.5f / 16.f) + 0.5f * xv.y;
  *(float2*)(dst + (size_t)row * NF + f) = o;
}

// ---------------- dense propagation GEMM (split-K) ----------------
// grid (79, 8). C^T partials: parts[(split*128 + n)*NPAD + m]

__global__ __launch_bounds__(256) void k_gemm(const u16* __restrict__ adjb,
    const u16* __restrict__ hTb, float* __restrict__ parts) {
  __shared__ __align__(16) u16 As[128 * 64];
  __shared__ __align__(16) u16 Bs[128 * 64];
  const int tid = threadIdx.x, w = tid >> 6, lane = tid & 63;
  const int l15 = lane & 15, g = lane >> 4;
  const int m0 = blockIdx.x * 128;
  const int split = blockIdx.y;
  const int wm = (w & 1) * 64, wn = (w >> 1) * 64;

  f32x4 zero = {0.f, 0.f, 0.f, 0.f};
  f32x4 acc[4][4];
#pragma unroll
  for (int mi = 0; mi < 4; mi++)
#pragma unroll
    for (int ni = 0; ni < 4; ni++) acc[mi][ni] = zero;

  for (int it = 0; it < 20; it++) {
    int kk = split * 1280 + it * 64;
    __syncthreads();
#pragma unroll
    for (int r = 0; r < 4; r++) {
      int s = r * 256 + tid;
      int row = s >> 3, u = s & 7;
      int uu = u ^ (row & 7);
      g2lds16(adjb + (size_t)(m0 + row) * KPAD + kk + uu * 8, (void*)(As + ((s & ~63) << 3)));
      g2lds16(hTb  + (size_t)row * KPAD + kk + uu * 8,        (void*)(Bs + ((s & ~63) << 3)));
    }
    __syncthreads();
#pragma unroll
    for (int ks = 0; ks < 2; ks++) {
      short8 af[4], bf[4];
#pragma unroll
      for (int mi = 0; mi < 4; mi++) {
        int row = wm + mi * 16 + l15;
        int uu = ((ks * 4 + g) ^ (row & 7));
        af[mi] = *(const short8*)(As + row * 64 + uu * 8);
      }
#pragma unroll
      for (int ni = 0; ni < 4; ni++) {
        int row = wn + ni * 16 + l15;
        int uu = ((ks * 4 + g) ^ (row & 7));
        bf[ni] = *(const short8*)(Bs + row * 64 + uu * 8);
      }
#pragma unroll
      for (int mi = 0; mi < 4; mi++)
#pragma unroll
        for (int ni = 0; ni < 4; ni++)
          acc[mi][ni] = __builtin_amdgcn_mfma_f32_16x16x32_bf16(af[mi], bf[ni], acc[mi][ni], 0, 0, 0);
    }
  }
#pragma unroll
  for (int mi = 0; mi < 4; mi++) {
#pragma unroll
    for (int ni = 0; ni < 4; ni++) {
      int n = wn + ni * 16 + l15;
      int k = m0 + wm + mi * 16 + g * 4;
      *(f32x4*)(parts + (size_t)(split * 128 + n) * NPAD + k) = acc[mi][ni];
    }
  }
}

__global__ __launch_bounds__(256) void k_reduce(const float* __restrict__ parts,
    const float* __restrict__ xTf, float* __restrict__ hTf, u16* __restrict__ hTb) {
  int idx = (blockIdx.x * 256 + threadIdx.x) * 4;
  int n = idx / KPAD;
  int k = idx - n * KPAD;
  float4 h = {0.f, 0.f, 0.f, 0.f};
  if (k < NPAD) {
    float4 s = {0.f, 0.f, 0.f, 0.f};
#pragma unroll
    for (int sp = 0; sp < 8; sp++) {
      float4 v = *(const float4*)(parts + (size_t)(sp * 128 + n) * NPAD + k);
      s.x += v.x; s.y += v.y; s.z += v.z; s.w += v.w;
    }
    float4 xv = *(const float4*)(xTf + (size_t)n * KPAD + k);
    h.x = 0.5f * s.x + 0.5f * xv.x;
    h.y = 0.5f * s.y + 0.5f * xv.y;
    h.z = 0.5f * s.z + 0.5f * xv.z;
    h.w = 0.5f * s.w + 0.5f * xv.w;
  }
  *(float4*)(hTf + (size_t)n * KPAD + k) = h;
  uint2 pk;
  pk.x = (u32)f2bf(h.x) | ((u32)f2bf(h.y) << 16);
  pk.y = (u32)f2bf(h.z) | ((u32)f2bf(h.w) << 16);
  *(uint2*)(hTb + (size_t)n * KPAD + k) = pk;
}

// ---------------- encoders / decoder ----------------

__global__ __launch_bounds__(256) void k_enc(const float* __restrict__ src, int sf, int si,
    const float* __restrict__ W, const float* __restrict__ b, float* __restrict__ out) {
  int w = threadIdx.x >> 6, o = threadIdx.x & 63;
  int row = blockIdx.x * 4 + w;
  if (row >= N_NODES) return;
  float acc = b[o];
#pragma unroll 8
  for (int f = 0; f < NF; f++) {
    float hv = src[(size_t)f * sf + (size_t)row * si];
    acc += hv * W[f * NH + o];
  }
  out[(size_t)row * NH + o] = fmaxf(acc, 0.f);
}

__global__ __launch_bounds__(256) void k_zres(const float* __restrict__ h1e,
    const float* __restrict__ h2e, const float* __restrict__ W2, const float* __restrict__ b2,
    const float* __restrict__ Wd, const float* __restrict__ bd, u16* __restrict__ resb) {
  int w = threadIdx.x >> 6, o = threadIdx.x & 63;
  int row = blockIdx.x * 4 + w;
  if (row >= NPAD) return;
  if (row >= N_NODES) {
    *(u32*)(resb + (size_t)row * NF + o * 2) = 0u;
    return;
  }
  float z1 = b2[o], z2 = b2[o];
#pragma unroll 8
  for (int c = 0; c < NH; c++) {
    float wv = W2[c * NH + o];
    z1 += h1e[(size_t)row * NH + c] * wv;
    z2 += h2e[(size_t)row * NH + c] * wv;
  }
  z1 = fmaxf(z1, 0.f); z2 = fmaxf(z2, 0.f);
  float r0 = bd[o], r1 = bd[o + 64];
#pragma unroll 4
  for (int c = 0; c < NH; c++) {
    float v1 = __shfl(z1, c), v2 = __shfl(z2, c);
    r0 += v1 * Wd[c * NF + o]      + v2 * Wd[(c + 64) * NF + o];
    r1 += v1 * Wd[c * NF + o + 64] + v2 * Wd[(c + 64) * NF + o + 64];
  }
  resb[(size_t)row * NF + o] = f2bf(r0);
  resb[(size_t)row * NF + o + 64] = f2bf(r1);
}

// ---------------- res @ res^T ----------------

__global__ __launch_bounds__(256) void k_out2(const u16* __restrict__ resb,
                                              float* __restrict__ out2) {
  const int tid = threadIdx.x, w = tid >> 6, lane = tid & 63;
  const int l15 = lane & 15, g = lane >> 4;
  const int m0 = blockIdx.x * 128 + (w & 1) * 64;
  const int n0 = blockIdx.y * 128 + (w >> 1) * 64;
  short8 af[4][4];
#pragma unroll
  for (int mi = 0; mi < 4; mi++)
#pragma unroll
    for (int ks = 0; ks < 4; ks++)
      af[mi][ks] = *(const short8*)(resb + (size_t)(m0 + mi * 16 + l15) * NF + ks * 32 + g * 8);
  f32x4 acc[4][4];
#pragma unroll
  for (int ni = 0; ni < 4; ni++) {
    short8 bq[4];
#pragma unroll
    for (int ks = 0; ks < 4; ks++)
      bq[ks] = *(const short8*)(resb + (size_t)(n0 + ni * 16 + l15) * NF + ks * 32 + g * 8);
#pragma unroll
    for (int mi = 0; mi < 4; mi++) {
      f32x4 a = {0.f, 0.f, 0.f, 0.f};
#pragma unroll
      for (int ks = 0; ks < 4; ks++)
        a = __builtin_amdgcn_mfma_f32_16x16x32_bf16(af[mi][ks], bq[ks], a, 0, 0, 0);
      acc[mi][ni] = a;
    }
  }
#pragma unroll
  for (int mi = 0; mi < 4; mi++) {
#pragma unroll
    for (int ni = 0; ni < 4; ni++) {
      int n = n0 + ni * 16 + l15;
      int mb = m0 + mi * 16 + g * 4;
      if (n < N_NODES) {
#pragma unroll
        for (int reg = 0; reg < 4; reg++) {
          int m = mb + reg;
          if (m < N_NODES) out2[(size_t)m * N_NODES + n] = acc[mi][ni][reg];
        }
      }
    }
  }
}

// ---------------- launch ----------------

extern "C" void kernel_launch(void* const* d_in, const int* in_sizes, int n_in,
                              void* d_out, int out_size, void* d_ws, size_t ws_size,
                              hipStream_t stream) {
  (void)in_sizes; (void)n_in; (void)out_size; (void)ws_size;
  const float* x     = (const float*)d_in[0];
  const float* adj   = (const float*)d_in[1];
  const float* Wenc  = (const float*)d_in[2];
  const float* benc  = (const float*)d_in[3];
  const float* Wenc2 = (const float*)d_in[4];
  const float* benc2 = (const float*)d_in[5];
  const float* Wdec  = (const float*)d_in[6];
  const float* bdec  = (const float*)d_in[7];

  char* ws = (char*)d_ws;
  size_t off = 0;
  auto alloc = [&](size_t bytes) {
    void* p = ws + off;
    off = (off + bytes + 255) & ~(size_t)255;
    return p;
  };
  u16*    adjb = (u16*)   alloc((size_t)NPAD * KPAD * 2);
  float*  parts= (float*) alloc((size_t)8 * 128 * NPAD * 4);
  float*  hTf  = (float*) alloc((size_t)128 * KPAD * 4);
  u16*    hTb  = (u16*)   alloc((size_t)128 * KPAD * 2);
  float*  xTf  = (float*) alloc((size_t)128 * KPAD * 4);
  u16*    xhi  = (u16*)   alloc((size_t)JPAD * NF * 2);
  u16*    xlo  = (u16*)   alloc((size_t)JPAD * NF * 2);
  float*  sq   = (float*) alloc((size_t)JPAD * 4);
  float2* cand = (float2*)alloc((size_t)NPAD * 256 * 8);
  int*    knn  = (int*)   alloc((size_t)N_NODES * 16 * 4);
  float*  h2a  = (float*) alloc((size_t)N_NODES * NF * 4);
  float*  h2b  = (float*) alloc((size_t)N_NODES * NF * 4);
  u16*    resb = (u16*)   alloc((size_t)NPAD * NF * 2);

  float* out0 = (float*)d_out;            // h1 encoded [10000,64]
  float* out1 = out0 + 640000;            // h2 encoded [10000,64]
  float* out2 = out0 + 1280000;           // res@res.T  [10000,10000]

  k_rowops   <<<dim3(JPAD / 4), dim3(256), 0, stream>>>(x, xhi, xlo, sq, h2a);
  k_transpose<<<dim3(KPAD / 32, 4), dim3(256), 0, stream>>>(x, xTf, hTf, hTb);
  k_adjcvt   <<<dim3(8192), dim3(256), 0, stream>>>(adj, adjb);

  k_gram <<<dim3(158, 4), dim3(256), 0, stream>>>(xhi, xlo, sq, cand);
  k_merge<<<dim3(2500), dim3(256), 0, stream>>>(cand, knn);

  float* h2s = h2a; float* h2d = h2b;
  for (int t = 0; t < 5; t++) {
    k_knnprop<<<dim3(2500), dim3(256), 0, stream>>>(h2s, x, knn, h2d);
    float* tmp = h2s; h2s = h2d; h2d = tmp;
  }

  for (int t = 0; t < 5; t++) {
    k_gemm  <<<dim3(79, 8), dim3(256), 0, stream>>>(adjb, hTb, parts);
    k_reduce<<<dim3(1280), dim3(256), 0, stream>>>(parts, xTf, hTf, hTb);
  }

  k_enc<<<dim3(2500), dim3(256), 0, stream>>>(hTf, KPAD, 1, Wenc, benc, out0);
  k_enc<<<dim3(2500), dim3(256), 0, stream>>>(h2s, 1, NF, Wenc, benc, out1);
  k_zres<<<dim3(2528), dim3(256), 0, stream>>>(out0, out1, Wenc2, benc2, Wdec, bdec, resb);
  k_out2<<<dim3(79, 79), dim3(256), 0, stream>>>(resb, out2);
}

// Round 2
// 1334.144 us; speedup vs baseline: 1.3330x; 1.3330x over previous
//
#include <hip/hip_runtime.h>
#include <stdint.h>

// Pipeline (round 2):
//  k_rowops    : x -> x_hi/x_lo bf16 (split precision), sq norms (pad rows sq=1e30)
//  k_transpose : x -> x^T fp32 + h^T fp32 init
//  k_pack8     : h^T fp32 -> fp8 (e4m3) init
//  k_adjcvt    : adj fp32 -> fp8 e4m3 scaled by 4096, padded [10112][10240]
//  k_gram      : hi/lo-MFMA Gram + top-4 threshold filter -> candidate buffers
//  k_merge     : wave-per-query exact top-16 from buffered candidates
//  5x k_knnprop: sparse propagation (16 nbrs)
//  5x (k_gemm fp8 split-K=8 + k_reduce): h = 0.5*adj@h + 0.5*x
//  k_enc x2, k_zres: encoders + decoder
//  k_out2      : res @ res^T via bf16 MFMA

typedef unsigned short u16;
typedef unsigned int u32;
typedef unsigned char u8;

#define N_NODES 10000
#define NPAD    10112   // 79*128
#define KPAD    10240   // 8*1280
#define JPAD    10240
#define NF      128
#define NH      64
#define CAP     96      // candidate buffer capacity per (q,split,g) lane-region
#define ADJ_SCALE 4096.0f
#define ADJ_INV   (0.5f / 4096.0f)

using short8 = __attribute__((ext_vector_type(8))) short;
using f32x4  = __attribute__((ext_vector_type(4))) float;

__device__ __forceinline__ u16 f2bf(float f) {
  u32 u = __float_as_uint(f);
  u += 0x7FFFu + ((u >> 16) & 1u);
  return (u16)(u >> 16);
}
__device__ __forceinline__ float bf2f(u16 h) { return __uint_as_float(((u32)h) << 16); }

__device__ __forceinline__ u32 pk4_fp8(float a, float b, float c, float d) {
  int v = __builtin_amdgcn_cvt_pk_fp8_f32(a, b, 0, false);
  v = __builtin_amdgcn_cvt_pk_fp8_f32(c, d, v, true);
  return (u32)v;
}

__device__ __forceinline__ void g2lds16(const void* g, void* l) {
  __builtin_amdgcn_global_load_lds((const __attribute__((address_space(1))) void*)g,
                                   (__attribute__((address_space(3))) void*)l, 16, 0, 0);
}

// ---------------- setup kernels ----------------

__global__ __launch_bounds__(256) void k_rowops(const float* __restrict__ x,
    u16* __restrict__ xhi, u16* __restrict__ xlo, float* __restrict__ sq) {
  int w = threadIdx.x >> 6, lane = threadIdx.x & 63;
  int row = blockIdx.x * 4 + w;
  if (row >= JPAD) return;
  int f = lane * 2;
  if (row < N_NODES) {
    float2 v = *(const float2*)(x + (size_t)row * NF + f);
    u16 h0 = f2bf(v.x), h1 = f2bf(v.y);
    float l0 = v.x - bf2f(h0), l1 = v.y - bf2f(h1);
    u16 e0 = f2bf(l0), e1 = f2bf(l1);
    *(u32*)(xhi + (size_t)row * NF + f) = (u32)h0 | ((u32)h1 << 16);
    *(u32*)(xlo + (size_t)row * NF + f) = (u32)e0 | ((u32)e1 << 16);
    float s = v.x * v.x + v.y * v.y;
#pragma unroll
    for (int o = 32; o > 0; o >>= 1) s += __shfl_xor(s, o);
    if (lane == 0) sq[row] = s;
  } else {
    *(u32*)(xhi + (size_t)row * NF + f) = 0u;
    *(u32*)(xlo + (size_t)row * NF + f) = 0u;
    if (lane == 0) sq[row] = 1.0e30f;   // pad rows rank last
  }
}

__global__ __launch_bounds__(256) void k_transpose(const float* __restrict__ x,
    float* __restrict__ xTf, float* __restrict__ hTf) {
  __shared__ float tile[32][33];
  int k0 = blockIdx.x * 32, f0 = blockIdx.y * 32;
  int c = threadIdx.x & 31, r4 = threadIdx.x >> 5;
#pragma unroll
  for (int i = 0; i < 4; i++) {
    int r = r4 + i * 8;
    int k = k0 + r;
    float v = 0.f;
    if (k < N_NODES) v = x[(size_t)k * NF + f0 + c];
    tile[r][c] = v;
  }
  __syncthreads();
#pragma unroll
  for (int i = 0; i < 4; i++) {
    int r = r4 + i * 8;
    int f = f0 + r;
    int k = k0 + c;
    float v = tile[c][r];
    size_t idx = (size_t)f * KPAD + k;
    xTf[idx] = v; hTf[idx] = v;
  }
}

__global__ __launch_bounds__(256) void k_pack8(const float* __restrict__ hTf,
                                               u8* __restrict__ hT8) {
  int idx = (blockIdx.x * 256 + threadIdx.x) * 4;
  float4 v = *(const float4*)(hTf + idx);
  *(u32*)(hT8 + idx) = pk4_fp8(v.x, v.y, v.z, v.w);
}

__global__ __launch_bounds__(256) void k_adjcvt(const float* __restrict__ adj,
                                                u8* __restrict__ out) {
  const int UNITS = NPAD * (KPAD / 8);
  for (int u = blockIdx.x * 256 + threadIdx.x; u < UNITS; u += gridDim.x * 256) {
    int r = u / (KPAD / 8);
    int c = (u - r * (KPAD / 8)) * 8;
    float v[8];
    if (r < N_NODES && c + 7 < N_NODES) {
      const float* p = adj + (size_t)r * N_NODES + c;
      float4 a = *(const float4*)p;
      float4 b = *(const float4*)(p + 4);
      v[0]=a.x; v[1]=a.y; v[2]=a.z; v[3]=a.w;
      v[4]=b.x; v[5]=b.y; v[6]=b.z; v[7]=b.w;
    } else {
#pragma unroll
      for (int t = 0; t < 8; t++) {
        int cc = c + t;
        v[t] = (r < N_NODES && cc < N_NODES) ? adj[(size_t)r * N_NODES + cc] : 0.f;
      }
    }
#pragma unroll
    for (int t = 0; t < 8; t++) v[t] *= ADJ_SCALE;
    uint2 pk;
    pk.x = pk4_fp8(v[0], v[1], v[2], v[3]);
    pk.y = pk4_fp8(v[4], v[5], v[6], v[7]);
    *(uint2*)(out + (size_t)r * KPAD + c) = pk;
  }
}

// ---------------- kNN: gram + threshold filter ----------------
// grid (158, 4). Wave w owns q = bx*64 + w*16 + (lane&15); g = lane>>4 covers
// j's with (j mod 16) in [g*4, g*4+4). Ranking key d' = sq_j - 2*dot.
// Keep per-lane sorted top-4 (values only); thr = max over the query's 4
// g-lanes of t4[3] (>= query 16th-best, provably). Candidates with d < thr
// appended to private global region cand[(q*16 + split*4 + g)*CAP + cnt].

__global__ __launch_bounds__(256) void k_gram(const u16* __restrict__ xhi,
    const u16* __restrict__ xlo, const float* __restrict__ sqg,
    float2* __restrict__ cand, u32* __restrict__ cnts) {
  __shared__ __align__(16) u16 shi[64 * 128];
  __shared__ __align__(16) u16 slo[64 * 128];
  __shared__ __align__(16) float ssq[64];
  const int tid = threadIdx.x, w = tid >> 6, lane = tid & 63;
  const int l15 = lane & 15, g = lane >> 4;
  const int q = blockIdx.x * 64 + w * 16 + l15;
  const int split = blockIdx.y;
  const size_t cbase = ((size_t)q * 16 + split * 4 + g) * CAP;

  short8 bh[4], bl[4];
#pragma unroll
  for (int ks = 0; ks < 4; ks++) {
    size_t off = (size_t)q * NF + ks * 32 + g * 8;
    bh[ks] = *(const short8*)(xhi + off);
    bl[ks] = *(const short8*)(xlo + off);
  }
  float t4[4] = {3.0e38f, 3.0e38f, 3.0e38f, 3.0e38f};
  float thr = 3.0e38f;
  u32 cnt = 0;

  for (int ch = 0; ch < 40; ch++) {
    int jbase = split * 2560 + ch * 64;
    __syncthreads();
#pragma unroll
    for (int r = 0; r < 4; r++) {
      int s = r * 256 + tid;
      int row = s >> 4, u = s & 15;
      int uu = u ^ (row & 7);
      size_t goff = (size_t)(jbase + row) * NF + uu * 8;
      g2lds16(xhi + goff, (void*)(shi + ((s & ~63) << 3)));
      g2lds16(xlo + goff, (void*)(slo + ((s & ~63) << 3)));
    }
    if (tid < 64) ssq[tid] = sqg[jbase + tid];
    __syncthreads();

#pragma unroll
    for (int sub = 0; sub < 4; sub++) {
      f32x4 acc = {0.f, 0.f, 0.f, 0.f};
#pragma unroll
      for (int ks = 0; ks < 4; ks++) {
        int row = sub * 16 + l15;
        int uu = ((ks * 4 + g) ^ (row & 7));
        int idx = row * 128 + uu * 8;
        short8 ah = *(const short8*)(shi + idx);
        short8 al = *(const short8*)(slo + idx);
        acc = __builtin_amdgcn_mfma_f32_16x16x32_bf16(ah, bh[ks], acc, 0, 0, 0);
        acc = __builtin_amdgcn_mfma_f32_16x16x32_bf16(ah, bl[ks], acc, 0, 0, 0);
        acc = __builtin_amdgcn_mfma_f32_16x16x32_bf16(al, bh[ks], acc, 0, 0, 0);
      }
      f32x4 sv = *(const f32x4*)(ssq + sub * 16 + g * 4);
      int jb = jbase + sub * 16 + g * 4;
#pragma unroll
      for (int reg = 0; reg < 4; reg++) {
        int j = jb + reg;
        float dd = sv[reg] - 2.0f * acc[reg];
        dd = (j == q) ? 3.0e38f : dd;
        if (dd < thr) {
          if (cnt < CAP) cand[cbase + cnt] = make_float2(dd, __int_as_float(j));
          cnt++;
        }
        bool c0 = dd < t4[0], c1 = dd < t4[1], c2 = dd < t4[2], c3 = dd < t4[3];
        t4[3] = c2 ? t4[2] : (c3 ? dd : t4[3]);
        t4[2] = c1 ? t4[1] : (c2 ? dd : t4[2]);
        t4[1] = c0 ? t4[0] : (c1 ? dd : t4[1]);
        t4[0] = c0 ? dd : t4[0];
      }
      float m = t4[3];
      m = fminf(m, 3.0e38f);
      m = fmaxf(m, __shfl_xor(m, 16));
      m = fmaxf(m, __shfl_xor(m, 32));
      thr = m;
    }
  }
  cnts[(size_t)q * 16 + split * 4 + g] = (cnt < CAP) ? cnt : CAP;
}

// wave per query: exact top-16 from <= 16*CAP buffered candidates
__global__ __launch_bounds__(256) void k_merge(const float2* __restrict__ cand,
    const u32* __restrict__ cnts, int* __restrict__ knn) {
  int w = threadIdx.x >> 6, lane = threadIdx.x & 63;
  int q = blockIdx.x * 4 + w;
  if (q >= N_NODES) return;
  int r = lane >> 2, s = lane & 3;           // region r=0..15, sub-lane s=0..3
  int cnt = (int)cnts[(size_t)q * 16 + r];
  const float2* cv = cand + ((size_t)q * 16 + r) * CAP;

  float t[16]; int ti[16];
#pragma unroll
  for (int i = 0; i < 16; i++) { t[i] = 3.0e38f; ti[i] = -1; }
  for (int e = s; e < cnt; e += 4) {
    float2 v = cv[e];
    float dd = v.x; int j = __float_as_int(v.y);
    if (j == q) continue;
    if (dd < t[15]) {
#pragma unroll
      for (int i = 15; i >= 1; --i) {
        bool ltp = dd < t[i - 1];
        bool ltc = dd < t[i];
        t[i]  = ltp ? t[i - 1] : (ltc ? dd : t[i]);
        ti[i] = ltp ? ti[i - 1] : (ltc ? j : ti[i]);
      }
      if (dd < t[0]) { t[0] = dd; ti[0] = j; }
    }
  }
  int myout = -1;
#pragma unroll
  for (int round = 0; round < 16; round++) {
    float d0 = t[0]; int j0 = ti[0];
#pragma unroll
    for (int off = 32; off > 0; off >>= 1) {
      float dn = __shfl_xor(d0, off); int jn = __shfl_xor(j0, off);
      bool take = (dn < d0) || (dn == d0 && jn < j0);
      d0 = take ? dn : d0; j0 = take ? jn : j0;
    }
    if (ti[0] == j0) {
#pragma unroll
      for (int i = 0; i < 15; i++) { t[i] = t[i + 1]; ti[i] = ti[i + 1]; }
      t[15] = 3.0e38f; ti[15] = -1;
    }
    if (lane == round) myout = j0;
  }
  if (lane < 16) knn[q * 16 + lane] = myout;
}

__global__ __launch_bounds__(256) void k_knnprop(const float* __restrict__ src,
    const float* __restrict__ x, const int* __restrict__ knn, float* __restrict__ dst) {
  int w = threadIdx.x >> 6, lane = threadIdx.x & 63;
  int row = blockIdx.x * 4 + w;
  if (row >= N_NODES) return;
  int f = lane * 2;
  float a0 = 0.f, a1 = 0.f;
#pragma unroll
  for (int nb = 0; nb < 16; nb++) {
    int j = knn[row * 16 + nb];
    float2 v = *(const float2*)(src + (size_t)j * NF + f);
    a0 += v.x; a1 += v.y;
  }
  float2 xv = *(const float2*)(x + (size_t)row * NF + f);
  float2 o;
  o.x = a0 * (0.5f / 16.f) + 0.5f * xv.x;
  o.y = a1 * (0.5f / 16.f) + 0.5f * xv.y;
  *(float2*)(dst + (size_t)row * NF + f) = o;
}

// ---------------- dense propagation GEMM (fp8, split-K=8) ----------------
// grid (79, 8). C^T partials: parts[(split*128 + n)*NPAD + m]

__global__ __launch_bounds__(256) void k_gemm(const u8* __restrict__ adj8,
    const u8* __restrict__ hT8, float* __restrict__ parts) {
  __shared__ __align__(16) u8 As[128 * 64];
  __shared__ __align__(16) u8 Bs[128 * 64];
  const int tid = threadIdx.x, w = tid >> 6, lane = tid & 63;
  const int l15 = lane & 15, g = lane >> 4;
  const int m0 = blockIdx.x * 128;
  const int split = blockIdx.y;
  const int wm = (w & 1) * 64, wn = (w >> 1) * 64;

  f32x4 zero = {0.f, 0.f, 0.f, 0.f};
  f32x4 acc[4][4];
#pragma unroll
  for (int mi = 0; mi < 4; mi++)
#pragma unroll
    for (int ni = 0; ni < 4; ni++) acc[mi][ni] = zero;

  for (int it = 0; it < 20; it++) {
    int kk = split * 1280 + it * 64;
    __syncthreads();
#pragma unroll
    for (int r = 0; r < 2; r++) {
      int s = r * 256 + tid;
      int row = s >> 2, u = s & 3;
      int uu = u ^ ((row >> 1) & 3);
      g2lds16(adj8 + (size_t)(m0 + row) * KPAD + kk + uu * 16, (void*)(As + ((s & ~63) << 4)));
    }
#pragma unroll
    for (int r = 0; r < 2; r++) {
      int s = r * 256 + tid;
      int row = s >> 2, u = s & 3;
      int uu = u ^ ((row >> 1) & 3);
      g2lds16(hT8 + (size_t)row * KPAD + kk + uu * 16, (void*)(Bs + ((s & ~63) << 4)));
    }
    __syncthreads();
#pragma unroll
    for (int ks = 0; ks < 2; ks++) {
      long af[4], bf[4];
#pragma unroll
      for (int mi = 0; mi < 4; mi++) {
        int row = wm + mi * 16 + l15;
        int u = (ks * 2 + (g >> 1)) ^ ((row >> 1) & 3);
        af[mi] = *(const long*)(As + row * 64 + u * 16 + (g & 1) * 8);
      }
#pragma unroll
      for (int ni = 0; ni < 4; ni++) {
        int row = wn + ni * 16 + l15;
        int u = (ks * 2 + (g >> 1)) ^ ((row >> 1) & 3);
        bf[ni] = *(const long*)(Bs + row * 64 + u * 16 + (g & 1) * 8);
      }
#pragma unroll
      for (int mi = 0; mi < 4; mi++)
#pragma unroll
        for (int ni = 0; ni < 4; ni++)
          acc[mi][ni] = __builtin_amdgcn_mfma_f32_16x16x32_fp8_fp8(af[mi], bf[ni], acc[mi][ni], 0, 0, 0);
    }
  }
#pragma unroll
  for (int mi = 0; mi < 4; mi++) {
#pragma unroll
    for (int ni = 0; ni < 4; ni++) {
      int n = wn + ni * 16 + l15;
      int m = m0 + wm + mi * 16 + g * 4;
      *(f32x4*)(parts + (size_t)(split * 128 + n) * NPAD + m) = acc[mi][ni];
    }
  }
}

__global__ __launch_bounds__(256) void k_reduce(const float* __restrict__ parts,
    const float* __restrict__ xTf, float* __restrict__ hTf, u8* __restrict__ hT8) {
  int idx = (blockIdx.x * 256 + threadIdx.x) * 4;
  int n = idx / KPAD;
  int k = idx - n * KPAD;
  float4 h = {0.f, 0.f, 0.f, 0.f};
  if (k < NPAD) {
    float4 s = {0.f, 0.f, 0.f, 0.f};
#pragma unroll
    for (int sp = 0; sp < 8; sp++) {
      float4 v = *(const float4*)(parts + (size_t)(sp * 128 + n) * NPAD + k);
      s.x += v.x; s.y += v.y; s.z += v.z; s.w += v.w;
    }
    float4 xv = *(const float4*)(xTf + (size_t)n * KPAD + k);
    h.x = ADJ_INV * s.x + 0.5f * xv.x;
    h.y = ADJ_INV * s.y + 0.5f * xv.y;
    h.z = ADJ_INV * s.z + 0.5f * xv.z;
    h.w = ADJ_INV * s.w + 0.5f * xv.w;
  }
  *(float4*)(hTf + (size_t)n * KPAD + k) = h;
  *(u32*)(hT8 + (size_t)n * KPAD + k) = pk4_fp8(h.x, h.y, h.z, h.w);
}

// ---------------- encoders / decoder ----------------

__global__ __launch_bounds__(256) void k_enc(const float* __restrict__ src, int sf, int si,
    const float* __restrict__ W, const float* __restrict__ b, float* __restrict__ out) {
  int w = threadIdx.x >> 6, o = threadIdx.x & 63;
  int row = blockIdx.x * 4 + w;
  if (row >= N_NODES) return;
  float acc = b[o];
#pragma unroll 8
  for (int f = 0; f < NF; f++) {
    float hv = src[(size_t)f * sf + (size_t)row * si];
    acc += hv * W[f * NH + o];
  }
  out[(size_t)row * NH + o] = fmaxf(acc, 0.f);
}

__global__ __launch_bounds__(256) void k_zres(const float* __restrict__ h1e,
    const float* __restrict__ h2e, const float* __restrict__ W2, const float* __restrict__ b2,
    const float* __restrict__ Wd, const float* __restrict__ bd, u16* __restrict__ resb) {
  int w = threadIdx.x >> 6, o = threadIdx.x & 63;
  int row = blockIdx.x * 4 + w;
  if (row >= NPAD) return;
  if (row >= N_NODES) {
    *(u32*)(resb + (size_t)row * NF + o * 2) = 0u;
    return;
  }
  float z1 = b2[o], z2 = b2[o];
#pragma unroll 8
  for (int c = 0; c < NH; c++) {
    float wv = W2[c * NH + o];
    z1 += h1e[(size_t)row * NH + c] * wv;
    z2 += h2e[(size_t)row * NH + c] * wv;
  }
  z1 = fmaxf(z1, 0.f); z2 = fmaxf(z2, 0.f);
  float r0 = bd[o], r1 = bd[o + 64];
#pragma unroll 4
  for (int c = 0; c < NH; c++) {
    float v1 = __shfl(z1, c), v2 = __shfl(z2, c);
    r0 += v1 * Wd[c * NF + o]      + v2 * Wd[(c + 64) * NF + o];
    r1 += v1 * Wd[c * NF + o + 64] + v2 * Wd[(c + 64) * NF + o + 64];
  }
  resb[(size_t)row * NF + o] = f2bf(r0);
  resb[(size_t)row * NF + o + 64] = f2bf(r1);
}

// ---------------- res @ res^T ----------------

__global__ __launch_bounds__(256) void k_out2(const u16* __restrict__ resb,
                                              float* __restrict__ out2) {
  const int tid = threadIdx.x, w = tid >> 6, lane = tid & 63;
  const int l15 = lane & 15, g = lane >> 4;
  const int m0 = blockIdx.x * 128 + (w & 1) * 64;
  const int n0 = blockIdx.y * 128 + (w >> 1) * 64;
  short8 af[4][4];
#pragma unroll
  for (int mi = 0; mi < 4; mi++)
#pragma unroll
    for (int ks = 0; ks < 4; ks++)
      af[mi][ks] = *(const short8*)(resb + (size_t)(m0 + mi * 16 + l15) * NF + ks * 32 + g * 8);
  f32x4 acc[4][4];
#pragma unroll
  for (int ni = 0; ni < 4; ni++) {
    short8 bq[4];
#pragma unroll
    for (int ks = 0; ks < 4; ks++)
      bq[ks] = *(const short8*)(resb + (size_t)(n0 + ni * 16 + l15) * NF + ks * 32 + g * 8);
#pragma unroll
    for (int mi = 0; mi < 4; mi++) {
      f32x4 a = {0.f, 0.f, 0.f, 0.f};
#pragma unroll
      for (int ks = 0; ks < 4; ks++)
        a = __builtin_amdgcn_mfma_f32_16x16x32_bf16(af[mi][ks], bq[ks], a, 0, 0, 0);
      acc[mi][ni] = a;
    }
  }
#pragma unroll
  for (int mi = 0; mi < 4; mi++) {
#pragma unroll
    for (int ni = 0; ni < 4; ni++) {
      int n = n0 + ni * 16 + l15;
      int mb = m0 + mi * 16 + g * 4;
      if (n < N_NODES) {
#pragma unroll
        for (int reg = 0; reg < 4; reg++) {
          int m = mb + reg;
          if (m < N_NODES) out2[(size_t)m * N_NODES + n] = acc[mi][ni][reg];
        }
      }
    }
  }
}

// ---------------- launch ----------------

extern "C" void kernel_launch(void* const* d_in, const int* in_sizes, int n_in,
                              void* d_out, int out_size, void* d_ws, size_t ws_size,
                              hipStream_t stream) {
  (void)in_sizes; (void)n_in; (void)out_size; (void)ws_size;
  const float* x     = (const float*)d_in[0];
  const float* adj   = (const float*)d_in[1];
  const float* Wenc  = (const float*)d_in[2];
  const float* benc  = (const float*)d_in[3];
  const float* Wenc2 = (const float*)d_in[4];
  const float* benc2 = (const float*)d_in[5];
  const float* Wdec  = (const float*)d_in[6];
  const float* bdec  = (const float*)d_in[7];

  char* ws = (char*)d_ws;
  size_t off = 0;
  auto alloc = [&](size_t bytes) {
    void* p = ws + off;
    off = (off + bytes + 255) & ~(size_t)255;
    return p;
  };
  u8*     adj8 = (u8*)    alloc((size_t)NPAD * KPAD);                 // 103.5 MB
  void*   uni  =          alloc((size_t)10240 * 16 * CAP * 8);        // 125.8 MB (cand | parts)
  float*  hTf  = (float*) alloc((size_t)128 * KPAD * 4);
  u8*     hT8  = (u8*)    alloc((size_t)128 * KPAD);
  float*  xTf  = (float*) alloc((size_t)128 * KPAD * 4);
  u16*    xhi  = (u16*)   alloc((size_t)JPAD * NF * 2);
  u16*    xlo  = (u16*)   alloc((size_t)JPAD * NF * 2);
  float*  sq   = (float*) alloc((size_t)JPAD * 4);
  u32*    cnts = (u32*)   alloc((size_t)10240 * 16 * 4);
  int*    knn  = (int*)   alloc((size_t)N_NODES * 16 * 4);
  float*  h2a  = (float*) alloc((size_t)N_NODES * NF * 4);
  float*  h2b  = (float*) alloc((size_t)N_NODES * NF * 4);
  u16*    resb = (u16*)   alloc((size_t)NPAD * NF * 2);

  float2* cand = (float2*)uni;   // kNN phase
  float*  parts= (float*) uni;   // dense-prop phase (after merge consumed cand)

  float* out0 = (float*)d_out;            // h1 encoded [10000,64]
  float* out1 = out0 + 640000;            // h2 encoded [10000,64]
  float* out2 = out0 + 1280000;           // res@res.T  [10000,10000]

  k_rowops   <<<dim3(JPAD / 4), dim3(256), 0, stream>>>(x, xhi, xlo, sq);
  k_transpose<<<dim3(KPAD / 32, 4), dim3(256), 0, stream>>>(x, xTf, hTf);
  k_pack8    <<<dim3(1280), dim3(256), 0, stream>>>(hTf, hT8);
  k_adjcvt   <<<dim3(8192), dim3(256), 0, stream>>>(adj, adj8);

  k_gram <<<dim3(158, 4), dim3(256), 0, stream>>>(xhi, xlo, sq, cand, cnts);
  k_merge<<<dim3(2500), dim3(256), 0, stream>>>(cand, cnts, knn);

  const float* h2s = x; float* h2d = h2a; float* h2o = h2b;
  for (int t = 0; t < 5; t++) {
    k_knnprop<<<dim3(2500), dim3(256), 0, stream>>>(h2s, x, knn, h2d);
    h2s = h2d; float* tmp = h2d; h2d = h2o; h2o = tmp;
  }

  for (int t = 0; t < 5; t++) {
    k_gemm  <<<dim3(79, 8), dim3(256), 0, stream>>>(adj8, hT8, parts);
    k_reduce<<<dim3(1280), dim3(256), 0, stream>>>(parts, xTf, hTf, hT8);
  }

  k_enc<<<dim3(2500), dim3(256), 0, stream>>>(hTf, KPAD, 1, Wenc, benc, out0);
  k_enc<<<dim3(2500), dim3(256), 0, stream>>>((const float*)h2s, 1, NF, Wenc, benc, out1);
  k_zres<<<dim3(2528), dim3(256), 0, stream>>>(out0, out1, Wenc2, benc2, Wdec, bdec, resb);
  k_out2<<<dim3(79, 79), dim3(256), 0, stream>>>(resb, out2);
}